// Round 2
// baseline (429.882 us; speedup 1.0000x reference)
//
#include <hip/hip_runtime.h>
#include <stdint.h>

// Problem: T=1024, B=32, C=1024, K=1024, E=16
//   out0 (T,B,C) fp32 = x + einsum('rboi,tbi->tbo', (resp@pw_w1).reshape(1,B,C,C), x)
//   out1 scalar loss
//
// R1 changes vs R0:
//   - gemm residual read from bf16 xb (saves 128 MB fp32 xf fetch; error budget ok)
//   - gemm 1D grid + XCD swizzle: each XCD works one batch at a time -> its
//     4 MB L2 holds exactly that batch's A(2MB)+B(2MB); kills 1.47x over-fetch
//   - staging pointers hoisted/incremented instead of recomputed per K-tile
//   - routing+loss fused into one 1-block kernel; convert+mix fused into one
//     partitioned-grid dispatch (5 kernels -> 3)

#define TBC   (1024*32*1024)   // 33554432

typedef __attribute__((ext_vector_type(8))) __bf16 bf16x8;
typedef __attribute__((ext_vector_type(4))) float  floatx4;

__device__ __forceinline__ unsigned short f2bf(float f) {
  unsigned u = __float_as_uint(f);
  unsigned r = u + 0x7fffu + ((u >> 16) & 1u);   // RNE
  return (unsigned short)(r >> 16);
}
__device__ __forceinline__ float bf2f(unsigned short u) {
  return __uint_as_float(((unsigned)u) << 16);
}

// global -> LDS async DMA, 16 B per lane; LDS dest is wave-uniform base,
// HW scatters lane i to base + i*16.
__device__ __forceinline__ void async16(const void* g, void* l) {
  __builtin_amdgcn_global_load_lds(
      (const __attribute__((address_space(1))) void*)(unsigned long long)(uintptr_t)g,
      (__attribute__((address_space(3))) void*)(unsigned int)(uintptr_t)l,
      16, 0, 0);
}

// ---------------- stage 1: routing + loss (single block) -------------------
__global__ __launch_bounds__(512) void routing_loss_kernel(
    const float* __restrict__ key, const float* __restrict__ aw,
    const float* __restrict__ ab, float* __restrict__ resp,
    float* __restrict__ loss_out) {
  __shared__ float logits[32][17];
  __shared__ float respS[32][17];
  __shared__ float imp[16];
  const int tid = threadIdx.x;
  const int e = tid & 15, b = tid >> 4;          // 512 threads = 32 b x 16 e
  const float4* k4 = (const float4*)(key + b * 1024);
  float acc = 0.f;
  #pragma unroll 4
  for (int kk = 0; kk < 256; ++kk) {
    const float4 kv = k4[kk];
    const int k0 = kk * 4;
    acc = fmaf(kv.x, aw[(k0 + 0) * 16 + e], acc);
    acc = fmaf(kv.y, aw[(k0 + 1) * 16 + e], acc);
    acc = fmaf(kv.z, aw[(k0 + 2) * 16 + e], acc);
    acc = fmaf(kv.w, aw[(k0 + 3) * 16 + e], acc);
  }
  logits[b][e] = acc + ab[e];
  __syncthreads();
  // per-thread softmax over its row
  float m = logits[b][0];
  #pragma unroll
  for (int j = 1; j < 16; ++j) m = fmaxf(m, logits[b][j]);
  float s = 0.f;
  #pragma unroll
  for (int j = 0; j < 16; ++j) s += expf(logits[b][j] - m);
  const float r = expf(logits[b][e] - m) / s;
  respS[b][e] = r;
  resp[b * 16 + e] = r;
  __syncthreads();
  if (tid < 16) {
    float si = 0.f;
    #pragma unroll
    for (int bb = 0; bb < 32; ++bb) si += respS[bb][tid];
    imp[tid] = si;
  }
  __syncthreads();
  if (tid == 0) {
    float mu = 0.f;
    #pragma unroll
    for (int j = 0; j < 16; ++j) mu += imp[j];
    mu *= (1.f / 16.f);
    float var = 0.f;
    #pragma unroll
    for (int j = 0; j < 16; ++j) { float d = imp[j] - mu; var += d * d; }
    var *= (1.f / 15.f);                         // ddof=1
    loss_out[0] = 0.01f * sqrtf(var) / mu;
  }
}

// ---------------- stage 2: fused convert (x->bf16) + mix -------------------
// blocks [0, 32768): convert 8388608 float4s of x -> xb
// blocks [32768, 33792): W[b] = sum_e resp[b,e]*pw_w1[e]  (bf16)
__global__ __launch_bounds__(256) void prep_kernel(
    const float4* __restrict__ x, ushort4* __restrict__ xb,
    const float4* __restrict__ pw, const float* __restrict__ resp,
    ushort4* __restrict__ W) {
  const int tid = threadIdx.x;
  if (blockIdx.x < 32768) {
    const int i = blockIdx.x * 256 + tid;
    float4 v = x[i];
    ushort4 o;
    o.x = f2bf(v.x); o.y = f2bf(v.y); o.z = f2bf(v.z); o.w = f2bf(v.w);
    xb[i] = o;
  } else {
    __shared__ float rs[512];
    rs[tid] = resp[tid];
    rs[tid + 256] = resp[tid + 256];
    __syncthreads();
    const int p = (blockIdx.x - 32768) * 256 + tid;   // 262144 vec4 positions
    float4 v[16];
    #pragma unroll
    for (int e = 0; e < 16; ++e) v[e] = pw[e * 262144 + p];
    #pragma unroll
    for (int b = 0; b < 32; ++b) {
      float ax = 0.f, ay = 0.f, az = 0.f, aww = 0.f;
      #pragma unroll
      for (int e = 0; e < 16; ++e) {
        const float r = rs[b * 16 + e];
        ax = fmaf(r, v[e].x, ax); ay = fmaf(r, v[e].y, ay);
        az = fmaf(r, v[e].z, az); aww = fmaf(r, v[e].w, aww);
      }
      ushort4 o;
      o.x = f2bf(ax); o.y = f2bf(ay); o.z = f2bf(az); o.w = f2bf(aww);
      W[(size_t)b * 262144 + p] = o;
    }
  }
}

// ---------------- stage 3: batched GEMM + residual -------------------------
// out[t,b,o] = bf2f(xb[t,b,o]) + sum_i xb[t,b,i] * W[b,o,i]
// 128x128 tile, BK=64. 1D grid with XCD swizzle: xcd=gid&7 gets batches
// 4*xcd..4*xcd+3 sequentially; one batch's A+B = 4 MB = one XCD L2.
__global__ __launch_bounds__(256, 2) void gemm_kernel(
    const unsigned short* __restrict__ xb,   // (T,B,C) bf16
    const unsigned short* __restrict__ Wb,   // (B,C,C) bf16 [b][o][i]
    float* __restrict__ out) {
  __shared__ unsigned short lds[2 * 128 * 64];   // A then B, 32 KB
  const int tid  = threadIdx.x;
  const int lane = tid & 63;
  const int wave = tid >> 6;
  const int wm = wave & 1, wn = wave >> 1;       // 2x2 waves of 64x64

  const int gid   = blockIdx.x;                  // 0..2047
  const int xcd   = gid & 7;
  const int local = gid >> 3;                    // 0..255
  const int b     = xcd * 4 + (local >> 6);
  const int sub   = local & 63;
  const int o0    = (sub & 7) * 128;
  const int t0    = (sub >> 3) * 128;

  unsigned short* ldsA = lds;
  unsigned short* ldsB = lds + 128 * 64;

  // staging source pointers (hoisted; advance by 64 elems per K-tile)
  const unsigned short* gA[4];
  const unsigned short* gB[4];
  #pragma unroll
  for (int j = 0; j < 4; ++j) {
    const int s  = j * 256 + tid;                // chunk slot 0..1023
    const int r  = s >> 3;                       // tile row
    const int cg = (s & 7) ^ (r & 7);            // XOR-swizzled source chunk
    gA[j] = xb + (size_t)(t0 + r) * 32768 + (size_t)b * 1024 + cg * 8;
    gB[j] = Wb + (size_t)b * 1048576 + (size_t)(o0 + r) * 1024 + cg * 8;
  }

  floatx4 acc[4][4];
  #pragma unroll
  for (int mi = 0; mi < 4; ++mi)
    #pragma unroll
    for (int ni = 0; ni < 4; ++ni)
      acc[mi][ni] = floatx4{0.f, 0.f, 0.f, 0.f};

  for (int kt = 0; kt < 1024; kt += 64) {
    if (kt) __syncthreads();                     // protect LDS overwrite
    #pragma unroll
    for (int j = 0; j < 4; ++j) {
      async16(gA[j], ldsA + (size_t)(j * 256 + wave * 64) * 8);
      async16(gB[j], ldsB + (size_t)(j * 256 + wave * 64) * 8);
      gA[j] += 64; gB[j] += 64;
    }
    __syncthreads();                             // drains vmcnt (staging visible)
    #pragma unroll
    for (int kk = 0; kk < 2; ++kk) {             // two K=32 MFMA steps
      bf16x8 af[4], bfr[4];
      #pragma unroll
      for (int mi = 0; mi < 4; ++mi) {
        const int r = wm * 64 + mi * 16 + (lane & 15);
        const int slot = (kk * 4 + (lane >> 4)) ^ (r & 7);
        af[mi] = *(const bf16x8*)(ldsA + r * 64 + slot * 8);
      }
      #pragma unroll
      for (int ni = 0; ni < 4; ++ni) {
        const int r = wn * 64 + ni * 16 + (lane & 15);
        const int slot = (kk * 4 + (lane >> 4)) ^ (r & 7);
        bfr[ni] = *(const bf16x8*)(ldsB + r * 64 + slot * 8);
      }
      #pragma unroll
      for (int mi = 0; mi < 4; ++mi)
        #pragma unroll
        for (int ni = 0; ni < 4; ++ni)
          acc[mi][ni] = __builtin_amdgcn_mfma_f32_16x16x32_bf16(af[mi], bfr[ni], acc[mi][ni], 0, 0, 0);
    }
  }

  // epilogue: C/D layout col=lane&15, row=quad*4+reg; residual from bf16 xb
  #pragma unroll
  for (int mi = 0; mi < 4; ++mi) {
    const int tb = t0 + wm * 64 + mi * 16 + (lane >> 4) * 4;
    #pragma unroll
    for (int ni = 0; ni < 4; ++ni) {
      const int o = o0 + wn * 64 + ni * 16 + (lane & 15);
      #pragma unroll
      for (int v = 0; v < 4; ++v) {
        const size_t idx = (size_t)(tb + v) * 32768 + (size_t)b * 1024 + o;
        out[idx] = acc[mi][ni][v] + bf2f(xb[idx]);
      }
    }
  }
}

extern "C" void kernel_launch(void* const* d_in, const int* in_sizes, int n_in,
                              void* d_out, int out_size, void* d_ws, size_t ws_size,
                              hipStream_t stream) {
  const float* x   = (const float*)d_in[0];   // (1024,32,1024)
  const float* key = (const float*)d_in[1];   // (1,32,1024)
  const float* aw  = (const float*)d_in[2];   // (1024,16)
  const float* ab  = (const float*)d_in[3];   // (16,)
  const float* pw  = (const float*)d_in[4];   // (16, 1048576)
  float* out = (float*)d_out;                 // 33554432 + 1

  char* ws = (char*)d_ws;
  unsigned short* Wb = (unsigned short*)ws;                    // 67108864 B
  unsigned short* xb = (unsigned short*)(ws + 67108864);       // 67108864 B
  float* resp        = (float*)(ws + 134217728);               // 2 KB

  routing_loss_kernel<<<1, 512, 0, stream>>>(key, aw, ab, resp, out + TBC);
  prep_kernel<<<33792, 256, 0, stream>>>((const float4*)x, (ushort4*)xb,
                                         (const float4*)pw, resp, (ushort4*)Wb);
  gemm_kernel<<<2048, 256, 0, stream>>>(xb, Wb, out);
}

// Round 3
// 400.869 us; speedup vs baseline: 1.0724x; 1.0724x over previous
//
#include <hip/hip_runtime.h>
#include <stdint.h>

// Problem: T=1024, B=32, C=1024, K=1024, E=16
//   out0 (T,B,C) fp32 = x + einsum('rboi,tbi->tbo', (resp@pw_w1).reshape(1,B,C,C), x)
//   out1 scalar loss
//
// R2 changes vs R1:
//   - gemm macro-tile 256t x 128o: stage {A0,A1,B} (48 KB LDS) per K-iter,
//     64 MFMA per barrier drain instead of 32 (drain is latency, not BW ->
//     amortize it). Grid 1024 blocks, XCD swizzle unchanged.
//   - routing back to 32 parallel blocks + tiny loss kernel (R1's 1-block
//     fused version cost ~30 us on a single CU).

#define TBC   (1024*32*1024)   // 33554432

typedef __attribute__((ext_vector_type(8))) __bf16 bf16x8;
typedef __attribute__((ext_vector_type(4))) float  floatx4;

__device__ __forceinline__ unsigned short f2bf(float f) {
  unsigned u = __float_as_uint(f);
  unsigned r = u + 0x7fffu + ((u >> 16) & 1u);   // RNE
  return (unsigned short)(r >> 16);
}
__device__ __forceinline__ float bf2f(unsigned short u) {
  return __uint_as_float(((unsigned)u) << 16);
}

// global -> LDS async DMA, 16 B per lane; LDS dest is wave-uniform base,
// HW scatters lane i to base + i*16.
__device__ __forceinline__ void async16(const void* g, void* l) {
  __builtin_amdgcn_global_load_lds(
      (const __attribute__((address_space(1))) void*)(unsigned long long)(uintptr_t)g,
      (__attribute__((address_space(3))) void*)(unsigned int)(uintptr_t)l,
      16, 0, 0);
}

// ---------------- stage 1: routing (one block per batch element) ----------
__global__ __launch_bounds__(256) void routing_kernel(
    const float* __restrict__ key, const float* __restrict__ aw,
    const float* __restrict__ ab, float* __restrict__ resp) {
  __shared__ float part[16][17];
  __shared__ float logit[16];
  const int b = blockIdx.x;
  const int tid = threadIdx.x;
  const int e = tid & 15, ks = tid >> 4;          // 16 k-slices of 64
  const float* kb = key + b * 1024 + ks * 64;
  float acc = 0.f;
  #pragma unroll 8
  for (int k = 0; k < 64; ++k)
    acc = fmaf(kb[k], aw[(ks * 64 + k) * 16 + e], acc);
  part[e][ks] = acc;
  __syncthreads();
  if (tid < 16) {
    float s = ab[tid];
    #pragma unroll
    for (int j = 0; j < 16; ++j) s += part[tid][j];
    logit[tid] = s;
  }
  __syncthreads();
  if (tid < 16) {
    float m = logit[0];
    #pragma unroll
    for (int j = 1; j < 16; ++j) m = fmaxf(m, logit[j]);
    float s = 0.f;
    #pragma unroll
    for (int j = 0; j < 16; ++j) s += expf(logit[j] - m);
    resp[b * 16 + tid] = expf(logit[tid] - m) / s;
  }
}

// ---------------- stage 2: loss --------------------------------------------
__global__ void loss_kernel(const float* __restrict__ resp, float* __restrict__ loss_out) {
  __shared__ float imp[16];
  const int tid = threadIdx.x;
  if (tid < 16) {
    float s = 0.f;
    for (int bb = 0; bb < 32; ++bb) s += resp[bb * 16 + tid];
    imp[tid] = s;
  }
  __syncthreads();
  if (tid == 0) {
    float mu = 0.f;
    for (int j = 0; j < 16; ++j) mu += imp[j];
    mu *= (1.f / 16.f);
    float var = 0.f;
    for (int j = 0; j < 16; ++j) { float d = imp[j] - mu; var += d * d; }
    var *= (1.f / 15.f);                      // ddof=1
    loss_out[0] = 0.01f * sqrtf(var) / mu;
  }
}

// ---------------- stage 3: fused convert (x->bf16) + mix -------------------
// blocks [0, 32768): convert 8388608 float4s of x -> xb
// blocks [32768, 33792): W[b] = sum_e resp[b,e]*pw_w1[e]  (bf16)
__global__ __launch_bounds__(256) void prep_kernel(
    const float4* __restrict__ x, ushort4* __restrict__ xb,
    const float4* __restrict__ pw, const float* __restrict__ resp,
    ushort4* __restrict__ W) {
  const int tid = threadIdx.x;
  if (blockIdx.x < 32768) {
    const int i = blockIdx.x * 256 + tid;
    float4 v = x[i];
    ushort4 o;
    o.x = f2bf(v.x); o.y = f2bf(v.y); o.z = f2bf(v.z); o.w = f2bf(v.w);
    xb[i] = o;
  } else {
    __shared__ float rs[512];
    rs[tid] = resp[tid];
    rs[tid + 256] = resp[tid + 256];
    __syncthreads();
    const int p = (blockIdx.x - 32768) * 256 + tid;   // 262144 vec4 positions
    float4 v[16];
    #pragma unroll
    for (int e = 0; e < 16; ++e) v[e] = pw[e * 262144 + p];
    #pragma unroll
    for (int b = 0; b < 32; ++b) {
      float ax = 0.f, ay = 0.f, az = 0.f, aww = 0.f;
      #pragma unroll
      for (int e = 0; e < 16; ++e) {
        const float r = rs[b * 16 + e];
        ax = fmaf(r, v[e].x, ax); ay = fmaf(r, v[e].y, ay);
        az = fmaf(r, v[e].z, az); aww = fmaf(r, v[e].w, aww);
      }
      ushort4 o;
      o.x = f2bf(ax); o.y = f2bf(ay); o.z = f2bf(az); o.w = f2bf(aww);
      W[(size_t)b * 262144 + p] = o;
    }
  }
}

// ---------------- stage 4: batched GEMM + residual -------------------------
// out[t,b,o] = bf2f(xb[t,b,o]) + sum_i xb[t,b,i] * W[b,o,i]
// Macro-tile 256t x 128o, BK=64: per K-iter stage A0(128x64)+A1(128x64)+
// B(128x64) = 48 KB LDS, then 64 MFMA per barrier drain (2x amortization).
// 1D grid, XCD swizzle: xcd=gid&7 works batches 4*xcd..4*xcd+3 sequentially
// (one batch's A+B = 4 MB = one XCD L2).
__global__ __launch_bounds__(256, 2) void gemm_kernel(
    const unsigned short* __restrict__ xb,   // (T,B,C) bf16
    const unsigned short* __restrict__ Wb,   // (B,C,C) bf16 [b][o][i]
    float* __restrict__ out) {
  __shared__ unsigned short lds[3 * 128 * 64];   // A0, A1, B : 48 KB
  const int tid  = threadIdx.x;
  const int lane = tid & 63;
  const int wave = tid >> 6;
  const int wm = wave & 1, wn = wave >> 1;       // 2x2 waves of 64x64 per half

  const int gid   = blockIdx.x;                  // 0..1023
  const int xcd   = gid & 7;
  const int local = gid >> 3;                    // 0..127
  const int b     = xcd * 4 + (local >> 5);
  const int sub   = local & 31;
  const int o0    = (sub & 7) * 128;
  const int t0    = (sub >> 3) * 256;

  unsigned short* ldsA0 = lds;
  unsigned short* ldsA1 = lds + 128 * 64;
  unsigned short* ldsB  = lds + 2 * 128 * 64;

  // staging source pointers (advance 64 elems per K-tile)
  const unsigned short* gA0[4];
  const unsigned short* gA1[4];
  const unsigned short* gB[4];
  #pragma unroll
  for (int j = 0; j < 4; ++j) {
    const int s  = j * 256 + tid;                // chunk slot 0..1023
    const int r  = s >> 3;                       // tile row
    const int cg = (s & 7) ^ (r & 7);            // XOR-swizzled source chunk
    gA0[j] = xb + (size_t)(t0 + r)       * 32768 + (size_t)b * 1024 + cg * 8;
    gA1[j] = xb + (size_t)(t0 + 128 + r) * 32768 + (size_t)b * 1024 + cg * 8;
    gB[j]  = Wb + (size_t)b * 1048576 + (size_t)(o0 + r) * 1024 + cg * 8;
  }

  floatx4 acc[2][4][4];
  #pragma unroll
  for (int th = 0; th < 2; ++th)
    #pragma unroll
    for (int mi = 0; mi < 4; ++mi)
      #pragma unroll
      for (int ni = 0; ni < 4; ++ni)
        acc[th][mi][ni] = floatx4{0.f, 0.f, 0.f, 0.f};

  for (int kt = 0; kt < 1024; kt += 64) {
    if (kt) __syncthreads();                     // protect LDS overwrite
    #pragma unroll
    for (int j = 0; j < 4; ++j) {
      const int dst = (j * 256 + wave * 64) * 8;
      async16(gA0[j], ldsA0 + dst);
      async16(gA1[j], ldsA1 + dst);
      async16(gB[j],  ldsB  + dst);
      gA0[j] += 64; gA1[j] += 64; gB[j] += 64;
    }
    __syncthreads();                             // drains vmcnt (staging visible)
    #pragma unroll
    for (int kk = 0; kk < 2; ++kk) {             // two K=32 MFMA steps
      bf16x8 bfr[4];
      #pragma unroll
      for (int ni = 0; ni < 4; ++ni) {
        const int r = wn * 64 + ni * 16 + (lane & 15);
        const int slot = (kk * 4 + (lane >> 4)) ^ (r & 7);
        bfr[ni] = *(const bf16x8*)(ldsB + r * 64 + slot * 8);
      }
      #pragma unroll
      for (int th = 0; th < 2; ++th) {
        unsigned short* ldsA = th ? ldsA1 : ldsA0;
        bf16x8 af[4];
        #pragma unroll
        for (int mi = 0; mi < 4; ++mi) {
          const int r = wm * 64 + mi * 16 + (lane & 15);
          const int slot = (kk * 4 + (lane >> 4)) ^ (r & 7);
          af[mi] = *(const bf16x8*)(ldsA + r * 64 + slot * 8);
        }
        #pragma unroll
        for (int mi = 0; mi < 4; ++mi)
          #pragma unroll
          for (int ni = 0; ni < 4; ++ni)
            acc[th][mi][ni] = __builtin_amdgcn_mfma_f32_16x16x32_bf16(af[mi], bfr[ni], acc[th][mi][ni], 0, 0, 0);
      }
    }
  }

  // epilogue: C/D layout col=lane&15, row=quad*4+reg; residual from bf16 xb
  #pragma unroll
  for (int th = 0; th < 2; ++th) {
    #pragma unroll
    for (int mi = 0; mi < 4; ++mi) {
      const int tb = t0 + th * 128 + wm * 64 + mi * 16 + (lane >> 4) * 4;
      #pragma unroll
      for (int ni = 0; ni < 4; ++ni) {
        const int o = o0 + wn * 64 + ni * 16 + (lane & 15);
        #pragma unroll
        for (int v = 0; v < 4; ++v) {
          const size_t idx = (size_t)(tb + v) * 32768 + (size_t)b * 1024 + o;
          out[idx] = acc[th][mi][ni][v] + bf2f(xb[idx]);
        }
      }
    }
  }
}

extern "C" void kernel_launch(void* const* d_in, const int* in_sizes, int n_in,
                              void* d_out, int out_size, void* d_ws, size_t ws_size,
                              hipStream_t stream) {
  const float* x   = (const float*)d_in[0];   // (1024,32,1024)
  const float* key = (const float*)d_in[1];   // (1,32,1024)
  const float* aw  = (const float*)d_in[2];   // (1024,16)
  const float* ab  = (const float*)d_in[3];   // (16,)
  const float* pw  = (const float*)d_in[4];   // (16, 1048576)
  float* out = (float*)d_out;                 // 33554432 + 1

  char* ws = (char*)d_ws;
  unsigned short* Wb = (unsigned short*)ws;                    // 67108864 B
  unsigned short* xb = (unsigned short*)(ws + 67108864);       // 67108864 B
  float* resp        = (float*)(ws + 134217728);               // 2 KB

  routing_kernel<<<32, 256, 0, stream>>>(key, aw, ab, resp);
  loss_kernel<<<1, 64, 0, stream>>>(resp, out + TBC);
  prep_kernel<<<33792, 256, 0, stream>>>((const float4*)x, (ushort4*)xb,
                                         (const float4*)pw, resp, (ushort4*)Wb);
  gemm_kernel<<<1024, 256, 0, stream>>>(xb, Wb, out);
}